// Round 4
// baseline (497.162 us; speedup 1.0000x reference)
//
#include <hip/hip_runtime.h>

#define F 128
#define NODES_PER_CHUNK 32
#define CHUNKS_PER_BLOCK 5   // 160 rows per block, 250 blocks covers 40000 rows

// native clang vector (accepted by __builtin_nontemporal_*; HIP float4 is not)
typedef float vfloat4 __attribute__((ext_vector_type(4)));

// fp32 -> bf16 round-to-nearest-even (inputs are normal floats here)
static __device__ __forceinline__ unsigned short f2bf(float f) {
    unsigned int u = __float_as_uint(f);
    u += 0x7FFFu + ((u >> 16) & 1u);
    return (unsigned short)(u >> 16);
}
static __device__ __forceinline__ float bf2f(unsigned short h) {
    return __uint_as_float(((unsigned int)h) << 16);
}

// ---------------------------------------------------------------------------
// Phase 1: q = x @ Wq, k = x @ Wk   (blockIdx.y = 0 -> q, 1 -> k)
// fp32 compute (exact), bf16 store. LDS: 64 KB W + 16 KB x-tile -> 2 blk/CU.
// x is read-once -> nontemporal loads (keep L2/L3 free for q/k gathers).
// ---------------------------------------------------------------------------
__global__ __launch_bounds__(256) void proj_kernel(
    const float* __restrict__ x,
    const float* __restrict__ Wq,
    const float* __restrict__ Wk,
    unsigned short* __restrict__ q,   // bf16 bits
    unsigned short* __restrict__ k)
{
    __shared__ float lds_w[F * F];                 // 64 KB
    __shared__ float lds_x[NODES_PER_CHUNK * F];   // 16 KB

    const int t   = threadIdx.x;
    const int isK = blockIdx.y;
    const float* __restrict__ W      = isK ? Wk : Wq;
    unsigned short* __restrict__ outp = isK ? k  : q;

    // stage W (16384 floats = 4096 float4) into LDS, coalesced
    {
        const vfloat4* w4 = (const vfloat4*)W;
        vfloat4* l4 = (vfloat4*)lds_w;
        #pragma unroll
        for (int i = 0; i < 16; ++i) l4[i * 256 + t] = w4[i * 256 + t];
    }

    const int cg = t & 31;   // column group: cols 4*cg .. 4*cg+3
    const int rg = t >> 5;   // row group (0..7): rows 4*rg .. 4*rg+3 within chunk

    for (int c = 0; c < CHUNKS_PER_BLOCK; ++c) {
        const int r0 = (blockIdx.x * CHUNKS_PER_BLOCK + c) * NODES_PER_CHUNK;

        __syncthreads();  // W staged (c==0) / previous chunk's x readers done
        {
            const vfloat4* x4 = (const vfloat4*)(x + (size_t)r0 * F);
            vfloat4* l4 = (vfloat4*)lds_x;
            #pragma unroll
            for (int i = 0; i < 4; ++i)
                l4[i * 256 + t] = __builtin_nontemporal_load(&x4[i * 256 + t]);
        }
        __syncthreads();

        float acc[4][4] = {};
        #pragma unroll 4
        for (int f4 = 0; f4 < 32; ++f4) {
            vfloat4 xv[4];
            #pragma unroll
            for (int r = 0; r < 4; ++r)
                xv[r] = *(const vfloat4*)&lds_x[(4 * rg + r) * F + 4 * f4];
            #pragma unroll
            for (int j = 0; j < 4; ++j) {
                const vfloat4 wv = *(const vfloat4*)&lds_w[(4 * f4 + j) * F + 4 * cg];
                #pragma unroll
                for (int r = 0; r < 4; ++r) {
                    const float xs = xv[r][j];
                    acc[r][0] += xs * wv[0];
                    acc[r][1] += xs * wv[1];
                    acc[r][2] += xs * wv[2];
                    acc[r][3] += xs * wv[3];
                }
            }
        }

        #pragma unroll
        for (int r = 0; r < 4; ++r) {
            ushort4 v;
            v.x = f2bf(acc[r][0]);
            v.y = f2bf(acc[r][1]);
            v.z = f2bf(acc[r][2]);
            v.w = f2bf(acc[r][3]);
            // q/k writes stay cached on purpose: edge kernel gathers them.
            *(ushort4*)&outp[(size_t)(r0 + 4 * rg + r) * F + 4 * cg] = v;
        }
    }
}

// ---------------------------------------------------------------------------
// Phase 2: out[p] = (1/sqrt(F)) * sum_f q[i,f] * w_ij[p,f] * k[j,f]
// 32 lanes per pair; w_ij is read-once -> nontemporal (keep it OUT of L3 so
// L3 bandwidth serves the q/k gathers). out store also nontemporal.
// ---------------------------------------------------------------------------
__global__ __launch_bounds__(256) void edge_kernel(
    const float* __restrict__ w_ij,
    const int*   __restrict__ idx_i,
    const int*   __restrict__ idx_j,
    const unsigned short* __restrict__ q,
    const unsigned short* __restrict__ k,
    float* __restrict__ out)
{
    const int t = blockIdx.x * 256 + threadIdx.x;
    const int p = t >> 5;   // pair index
    const int l = t & 31;   // lane within half-wave

    const int i = idx_i[p];
    const int j = idx_j[p];

    const vfloat4 wv = __builtin_nontemporal_load(
                           (const vfloat4*)&w_ij[(size_t)p * F + 4 * l]);
    const ushort4 qv = *(const ushort4*)&q[(size_t)i * F + 4 * l];
    const ushort4 kv = *(const ushort4*)&k[(size_t)j * F + 4 * l];

    float s = bf2f(qv.x) * bf2f(kv.x) * wv[0]
            + bf2f(qv.y) * bf2f(kv.y) * wv[1]
            + bf2f(qv.z) * bf2f(kv.z) * wv[2]
            + bf2f(qv.w) * bf2f(kv.w) * wv[3];

    s += __shfl_xor(s, 16);
    s += __shfl_xor(s, 8);
    s += __shfl_xor(s, 4);
    s += __shfl_xor(s, 2);
    s += __shfl_xor(s, 1);

    if (l == 0)
        __builtin_nontemporal_store(s * 0.088388347648318447f, &out[p]);
}

extern "C" void kernel_launch(void* const* d_in, const int* in_sizes, int n_in,
                              void* d_out, int out_size, void* d_ws, size_t ws_size,
                              hipStream_t stream) {
    const float* x     = (const float*)d_in[0];
    const float* w_ij  = (const float*)d_in[1];
    const int*   idx_i = (const int*)d_in[2];
    const int*   idx_j = (const int*)d_in[3];
    const float* Wq    = (const float*)d_in[4];
    const float* Wk    = (const float*)d_in[5];
    float* out = (float*)d_out;

    const int n_nodes = in_sizes[0] / F;   // 40000
    const int n_pairs = in_sizes[2];       // 640000

    unsigned short* q = (unsigned short*)d_ws;
    unsigned short* k = q + (size_t)n_nodes * F;

    dim3 g1(n_nodes / (NODES_PER_CHUNK * CHUNKS_PER_BLOCK), 2);
    proj_kernel<<<g1, 256, 0, stream>>>(x, Wq, Wk, q, k);

    int g2 = (n_pairs * 32) / 256;
    edge_kernel<<<g2, 256, 0, stream>>>(w_ij, idx_i, idx_j, q, k, out);
}

// Round 5
// 486.339 us; speedup vs baseline: 1.0223x; 1.0223x over previous
//
#include <hip/hip_runtime.h>

#define F 128
#define NODES_PER_CHUNK 32
#define CHUNKS_PER_BLOCK 5   // 160 rows per block, 250 blocks covers 40000 rows
#define PAIRS_PER_BLOCK 32   // edge kernel: 32 pairs/block, 4 per half-wave

// fp32 -> bf16 round-to-nearest-even (inputs are normal floats here)
static __device__ __forceinline__ unsigned short f2bf(float f) {
    unsigned int u = __float_as_uint(f);
    u += 0x7FFFu + ((u >> 16) & 1u);
    return (unsigned short)(u >> 16);
}
static __device__ __forceinline__ float bf2f(unsigned short h) {
    return __uint_as_float(((unsigned int)h) << 16);
}

// ---------------------------------------------------------------------------
// Phase 1: q = x @ Wq, k = x @ Wk   (blockIdx.y = 0 -> q, 1 -> k)
// fp32 compute (exact), bf16 store. LDS: 64 KB W + 16 KB x-tile -> 2 blk/CU.
// (R4 lesson: nontemporal hints regressed — plain cached loads.)
// ---------------------------------------------------------------------------
__global__ __launch_bounds__(256) void proj_kernel(
    const float* __restrict__ x,
    const float* __restrict__ Wq,
    const float* __restrict__ Wk,
    unsigned short* __restrict__ q,   // bf16 bits
    unsigned short* __restrict__ k)
{
    __shared__ float lds_w[F * F];                 // 64 KB
    __shared__ float lds_x[NODES_PER_CHUNK * F];   // 16 KB

    const int t   = threadIdx.x;
    const int isK = blockIdx.y;
    const float* __restrict__ W      = isK ? Wk : Wq;
    unsigned short* __restrict__ outp = isK ? k  : q;

    // stage W (16384 floats = 4096 float4) into LDS, coalesced
    {
        const float4* w4 = (const float4*)W;
        float4* l4 = (float4*)lds_w;
        #pragma unroll
        for (int i = 0; i < 16; ++i) l4[i * 256 + t] = w4[i * 256 + t];
    }

    const int cg = t & 31;   // column group: cols 4*cg .. 4*cg+3
    const int rg = t >> 5;   // row group (0..7): rows 4*rg .. 4*rg+3 within chunk

    for (int c = 0; c < CHUNKS_PER_BLOCK; ++c) {
        const int r0 = (blockIdx.x * CHUNKS_PER_BLOCK + c) * NODES_PER_CHUNK;

        __syncthreads();  // W staged (c==0) / previous chunk's x readers done
        {
            const float4* x4 = (const float4*)(x + (size_t)r0 * F);
            float4* l4 = (float4*)lds_x;
            #pragma unroll
            for (int i = 0; i < 4; ++i) l4[i * 256 + t] = x4[i * 256 + t];
        }
        __syncthreads();

        float acc[4][4] = {};
        #pragma unroll 4
        for (int f4 = 0; f4 < 32; ++f4) {
            float4 xv[4];
            #pragma unroll
            for (int r = 0; r < 4; ++r)
                xv[r] = *(const float4*)&lds_x[(4 * rg + r) * F + 4 * f4];
            #pragma unroll
            for (int j = 0; j < 4; ++j) {
                const float4 wv = *(const float4*)&lds_w[(4 * f4 + j) * F + 4 * cg];
                #pragma unroll
                for (int r = 0; r < 4; ++r) {
                    const float xs = ((const float*)&xv[r])[j];
                    acc[r][0] += xs * wv.x;
                    acc[r][1] += xs * wv.y;
                    acc[r][2] += xs * wv.z;
                    acc[r][3] += xs * wv.w;
                }
            }
        }

        #pragma unroll
        for (int r = 0; r < 4; ++r) {
            ushort4 v;
            v.x = f2bf(acc[r][0]);
            v.y = f2bf(acc[r][1]);
            v.z = f2bf(acc[r][2]);
            v.w = f2bf(acc[r][3]);
            *(ushort4*)&outp[(size_t)(r0 + 4 * rg + r) * F + 4 * cg] = v;
        }
    }
}

// ---------------------------------------------------------------------------
// Phase 2: out[p] = (1/sqrt(F)) * sum_f q[i,f] * w_ij[p,f] * k[j,f]
// MLP restructure: block owns 32 pairs; one wave stages all 64 indices into
// LDS (coalesced), then each half-wave processes 4 pairs UNROLLED — 12
// independent VMEM loads in flight per thread before any use.
// ---------------------------------------------------------------------------
__global__ __launch_bounds__(256) void edge_kernel(
    const float* __restrict__ w_ij,
    const int*   __restrict__ idx_i,
    const int*   __restrict__ idx_j,
    const unsigned short* __restrict__ q,
    const unsigned short* __restrict__ k,
    float* __restrict__ out)
{
    __shared__ int sidx[2 * PAIRS_PER_BLOCK];   // [0..31]=i, [32..63]=j

    const int p0 = blockIdx.x * PAIRS_PER_BLOCK;
    const int t  = threadIdx.x;

    if (t < 64) {
        // lanes 0..31: idx_i[p0..p0+31]; lanes 32..63: idx_j[p0..p0+31]
        sidx[t] = (t < 32) ? idx_i[p0 + t] : idx_j[p0 + t - 32];
    }
    __syncthreads();

    const int hw = t >> 5;   // half-wave id 0..7 -> pairs hw*4 .. hw*4+3
    const int l  = t & 31;   // lane within half-wave

    float4  wv[4];
    ushort4 qv[4], kv[4];
    #pragma unroll
    for (int u = 0; u < 4; ++u) {
        const int pp = hw * 4 + u;
        const int i = sidx[pp];
        const int j = sidx[PAIRS_PER_BLOCK + pp];
        wv[u] = *(const float4*)&w_ij[(size_t)(p0 + pp) * F + 4 * l];
        qv[u] = *(const ushort4*)&q[(size_t)i * F + 4 * l];
        kv[u] = *(const ushort4*)&k[(size_t)j * F + 4 * l];
    }

    #pragma unroll
    for (int u = 0; u < 4; ++u) {
        float s = bf2f(qv[u].x) * bf2f(kv[u].x) * wv[u].x
                + bf2f(qv[u].y) * bf2f(kv[u].y) * wv[u].y
                + bf2f(qv[u].z) * bf2f(kv[u].z) * wv[u].z
                + bf2f(qv[u].w) * bf2f(kv[u].w) * wv[u].w;
        s += __shfl_xor(s, 16);
        s += __shfl_xor(s, 8);
        s += __shfl_xor(s, 4);
        s += __shfl_xor(s, 2);
        s += __shfl_xor(s, 1);
        if (l == 0) out[p0 + hw * 4 + u] = s * 0.088388347648318447f;
    }
}

extern "C" void kernel_launch(void* const* d_in, const int* in_sizes, int n_in,
                              void* d_out, int out_size, void* d_ws, size_t ws_size,
                              hipStream_t stream) {
    const float* x     = (const float*)d_in[0];
    const float* w_ij  = (const float*)d_in[1];
    const int*   idx_i = (const int*)d_in[2];
    const int*   idx_j = (const int*)d_in[3];
    const float* Wq    = (const float*)d_in[4];
    const float* Wk    = (const float*)d_in[5];
    float* out = (float*)d_out;

    const int n_nodes = in_sizes[0] / F;   // 40000
    const int n_pairs = in_sizes[2];       // 640000

    unsigned short* q = (unsigned short*)d_ws;
    unsigned short* k = q + (size_t)n_nodes * F;

    dim3 g1(n_nodes / (NODES_PER_CHUNK * CHUNKS_PER_BLOCK), 2);
    proj_kernel<<<g1, 256, 0, stream>>>(x, Wq, Wk, q, k);

    int g2 = n_pairs / PAIRS_PER_BLOCK;
    edge_kernel<<<g2, 256, 0, stream>>>(w_ij, idx_i, idx_j, q, k, out);
}